// Round 21
// baseline (140.722 us; speedup 1.0000x reference)
//
#include <hip/hip_runtime.h>
#include <hip/hip_bf16.h>

// ---- problem constants ----
#define OUT_CH   31
#define COEF_LEN 7688                 // 31*31*8
#define NPIX     16384                // 128*128
#define CHUNKS   31                   // KAN input channels (independent param groups)
#define NFRG     24                   // param fragments per chunk (384 padded M rows)
#define NR       9                    // K-steps: r = ky*3+kx; k-in-step = conv channel ci
#define FRAG_U16 512                  // u16 per fragment (64 lanes x 8)
#define STEP_U16 (NFRG*FRAG_U16)      // 12288 u16 per (chunk,r) step
#define BP3_B    ((size_t)CHUNKS*NR*STEP_U16*2)        // 6,856,704
#define P1_B     ((size_t)OUT_CH*NPIX*4)               // 2,031,616
#define WS_NEED  (BP3_B + P1_B)                        // 8,888,320

// dynamic-LDS layout (103,904 B total; 1 block/CU)
#define SLAB_OFF  0                   // u16 [3][130][40] = 31,200 B
#define WT_OFF    31200               // f32 [128][132]   = 67,584 B
#define SLT_OFF   98784               // u16 [128][20]    =  5,120 B
#define LDS_BYTES 103904

using f32x4 = __attribute__((ext_vector_type(4))) float;
using s16x8 = __attribute__((ext_vector_type(8))) short;

__device__ __forceinline__ unsigned short f2bf(float f) {
    unsigned int u = __float_as_uint(f);
    unsigned int r = (u + 0x7FFFu + ((u >> 16) & 1u)) >> 16;
    return (unsigned short)r;
}

// ---------------------------------------------------------------------------
// Pack gen_w/gen_b into bf16 A-fragment layout (R14-proven, unchanged).
// Bias folded into GEMM: slab slot 31 = 1.0; A[ci=31] at r==4 carries gb[p].
//  bp3[i][r][f][lane][8] bf16.  M-row m = lane&15; k-in-step ci = (lane>>4)*8+jj.
//  param identity: o = (m>>2)*8 + f/3, jslot = (f%3)*4 + (m&3)
//    jslot 0..7 = coef j, 8 = univ, 9 = res, 10..11 = zero pad
// ---------------------------------------------------------------------------
__global__ void pack_kernel(const float* __restrict__ gw, const float* __restrict__ gb,
                            unsigned short* __restrict__ bp) {
    const int NMAIN = CHUNKS * NFRG * 64;          // 47616
    int tt = blockIdx.x * 256 + threadIdx.x;
    if (tt >= NMAIN) return;
    int lane = tt & 63;
    int u = tt >> 6;
    int f = u % NFRG;
    int i = u / NFRG;
    int m = lane & 15, q8 = lane >> 4;
    int o = (m >> 2) * 8 + f / 3;
    int jslot = (f % 3) * 4 + (m & 3);
    int p = -1;
    if (o < OUT_CH && jslot < 10) {
        if (jslot < 8)       p = i * 248 + o * 8 + jslot;
        else if (jslot == 8) p = COEF_LEN + i * 31 + o;
        else                 p = COEF_LEN + 961 + i * 31 + o;
    }
    s16x8 vr[NR];
    #pragma unroll
    for (int r = 0; r < NR; ++r)
        #pragma unroll
        for (int jj = 0; jj < 8; ++jj) vr[r][jj] = 0;
    #pragma unroll
    for (int jj = 0; jj < 8; ++jj) {
        int ci = q8 * 8 + jj;
        if (p >= 0) {
            if (ci < 31) {
                const float* gr = gw + (long)p * 279 + ci * 9;
                #pragma unroll
                for (int r = 0; r < NR; ++r) vr[r][jj] = (short)f2bf(gr[r]);
            } else {
                vr[4][jj] = (short)f2bf(gb[p]);   // bias channel, center tap only
            }
        }
    }
    #pragma unroll
    for (int r = 0; r < NR; ++r)
        *reinterpret_cast<s16x8*>(bp + (((size_t)i * NR + r) * NFRG + f) * FRAG_U16 + lane * 8) = vr[r];
}

// ---------------------------------------------------------------------------
// Fused conv-GEMM + KAN epilogue. R20 structure (96 us main, 1024-thr,
// 4 waves/SIMD, 1 block/CU) RETILED to cut the LDS B-read pipe (the R20
// bottleneck: 8 fi-waves re-read the same B frags -> 768 cyc/CU/r-step vs
// 240 MFMA): 16 waves = 4 fi-groups (6 frags, 96 param rows) x 4 px-quarters
// (32 px). B-reads/wave/r-step: 4 -> 2 ds_read_b128 (total LDS ~46 -> 23 us).
// A-frag redundancy 2x -> 4x per block, but the 24 KB r-step working set is
// L1-resident so extra reads are L1 hits. Lane owns TWO output channels
// (o = q*8 + 2fi + t, t = sub-triple fl/3). acc[6][2]+pa[2][6] ~ 120 regs
// nominal (R8 measured this mix at 116); cap 128 under (1024,1).
// Everything else R20-verbatim (pack, slab, tables, cg L2 pin, partials).
// ---------------------------------------------------------------------------
__global__ void __launch_bounds__(1024, 1)
main_kernel(const float* __restrict__ x, const unsigned short* __restrict__ bp3,
            float* __restrict__ dst0, float* __restrict__ dst1,
            int two_cg, int c0_in, int nc_in, int add_in) {
    extern __shared__ char smem[];
    unsigned short* slab = (unsigned short*)(smem + SLAB_OFF);  // [3][130][40]
    float* Wt = (float*)(smem + WT_OFF);                        // [128][132]
    unsigned short* SLt = (unsigned short*)(smem + SLT_OFF);    // [128][20]

    const int tid = threadIdx.x;
    const int bid = blockIdx.x;
    int row, c0, nc, addf;
    float* dst;
    if (two_cg) {
        int cg = bid & 1;          // XCD = bid%8 -> cg fixed per XCD (L2 pin)
        row = bid >> 1;
        c0 = cg ? 16 : 0;
        nc = cg ? 15 : 16;
        dst = cg ? dst1 : dst0;
        addf = 0;
    } else {
        row = bid;
        c0 = c0_in; nc = nc_in; dst = dst0; addf = add_in;
    }

    // slab: rows row-1..row+1, cols -1..128; slot31 = 1.0 (bias col)
    for (int idx = tid; idx < 3 * 130 * 40; idx += 1024) {
        int slot = idx % 40;
        int t = idx / 40;
        int cc = t % 130;
        int rr = t / 130;
        int hh = row - 1 + rr, ww = cc - 1;
        unsigned short v = 0;
        if (slot < 31) {
            if ((unsigned)hh < 128u && (unsigned)ww < 128u)
                v = f2bf(x[slot * NPIX + hh * 128 + ww]);
        } else if (slot == 31) {
            v = 0x3F80;   // 1.0 bf16
        }
        slab[(rr * 130 + cc) * 40 + slot] = v;
    }

    // spline/silu tables: once per (pixel, chunk), from f32 x (center pixels)
    for (int idx = tid; idx < nc * 128; idx += 1024) {
        int px = idx & 127;
        int k = idx >> 7;
        float xv = x[(size_t)(c0 + k) * NPIX + row * 128 + px];
        float u5 = (xv + 1.0f) * 2.5f;
        float cf = fminf(fmaxf(floorf(u5), 0.f), 4.f);
        int ccb = (int)cf;
        float t = u5 - cf;
        float omt = 1.f - t;
        float t2v = t * t, t3v = t2v * t;
        float bw0 = omt * omt * omt * (1.f / 6.f);
        float bw3 = t3v * (1.f / 6.f);
        float bw1 = 0.5f * t3v - t2v + (2.f / 3.f);
        float bw2 = 1.f - bw0 - bw1 - bw3;         // partition of unity
        float* wr = Wt + px * 132 + k * 8;
        *reinterpret_cast<f32x4*>(wr) = (f32x4){0.f, 0.f, 0.f, 0.f};
        *reinterpret_cast<f32x4*>(wr + 4) = (f32x4){0.f, 0.f, 0.f, 0.f};
        wr[ccb] = bw0; wr[ccb + 1] = bw1; wr[ccb + 2] = bw2; wr[ccb + 3] = bw3;
        SLt[px * 20 + k] = f2bf(xv / (1.f + __expf(-xv)));
    }
    __syncthreads();
    // ---- no further barriers; slab/Wt/SLt are read-only below ----

    const int lane = tid & 63;
    const int w = tid >> 6;               // 0..15
    const int fi = w & 3;                 // frag sextet [6fi, 6fi+6)
    const int xq = w >> 2;                // pixel quarter: cols [32*xq, 32*xq+32)
    const int q = lane >> 4;
    const int pix16 = lane & 15;
    const char* slabb = (const char*)slab;

    int sa[2];
    #pragma unroll
    for (int pg = 0; pg < 2; ++pg)
        sa[pg] = (xq * 32 + pg * 16 + pix16) * 80 + q * 16;   // slab byte offsets

    float oreg[2][2];   // [t = sub-triple][pg]
    oreg[0][0] = oreg[0][1] = oreg[1][0] = oreg[1][1] = 0.f;

    #pragma unroll 1
    for (int k = 0; k < nc; ++k) {
        const unsigned short* aw = bp3
            + ((size_t)(c0 + k) * NR * NFRG + fi * 6) * FRAG_U16 + lane * 8;

        s16x8 pa[2][6];
        #pragma unroll
        for (int fl = 0; fl < 6; ++fl)
            pa[0][fl] = *reinterpret_cast<const s16x8*>(aw + fl * FRAG_U16);

        f32x4 acc[6][2];
        #pragma unroll
        for (int fl = 0; fl < 6; ++fl)
            #pragma unroll
            for (int pg = 0; pg < 2; ++pg)
                acc[fl][pg] = (f32x4){0.f, 0.f, 0.f, 0.f};   // bias comes via GEMM

        #pragma unroll
        for (int r = 0; r < NR; ++r) {
            if (r + 1 < NR) {    // reg-dbuf prefetch; static index (r unrolled)
                #pragma unroll
                for (int fl = 0; fl < 6; ++fl)
                    pa[(r + 1) & 1][fl] = *reinterpret_cast<const s16x8*>(
                        aw + (r + 1) * STEP_U16 + fl * FRAG_U16);
            }
            const int roff = ((r / 3) * 130 + (r % 3)) * 80;
            s16x8 pbv[2];
            #pragma unroll
            for (int pg = 0; pg < 2; ++pg)
                pbv[pg] = *reinterpret_cast<const s16x8*>(slabb + sa[pg] + roff);

            __builtin_amdgcn_s_setprio(1);
            #pragma unroll
            for (int fl = 0; fl < 6; ++fl)
                #pragma unroll
                for (int pg = 0; pg < 2; ++pg)
                    acc[fl][pg] = __builtin_amdgcn_mfma_f32_16x16x32_bf16(
                        pa[r & 1][fl], pbv[pg], acc[fl][pg], 0, 0, 0);
            __builtin_amdgcn_s_setprio(0);
        }

        // table epilogue: per pg, two sub-triples t (each 10 fma)
        #pragma unroll
        for (int pg = 0; pg < 2; ++pg) {
            const int px = xq * 32 + pg * 16 + pix16;
            const float* wr = Wt + px * 132 + k * 8;
            f32x4 wlo = *reinterpret_cast<const f32x4*>(wr);
            f32x4 whi = *reinterpret_cast<const f32x4*>(wr + 4);
            unsigned short slb = SLt[px * 20 + k];
            float sl = __uint_as_float((unsigned)slb << 16);
            #pragma unroll
            for (int t = 0; t < 2; ++t) {
                float sp = wlo[0] * acc[3 * t + 0][pg][0];
                sp = fmaf(wlo[1], acc[3 * t + 0][pg][1], sp);
                sp = fmaf(wlo[2], acc[3 * t + 0][pg][2], sp);
                sp = fmaf(wlo[3], acc[3 * t + 0][pg][3], sp);
                sp = fmaf(whi[0], acc[3 * t + 1][pg][0], sp);
                sp = fmaf(whi[1], acc[3 * t + 1][pg][1], sp);
                sp = fmaf(whi[2], acc[3 * t + 1][pg][2], sp);
                sp = fmaf(whi[3], acc[3 * t + 1][pg][3], sp);
                oreg[t][pg] = fmaf(acc[3 * t + 2][pg][0], sp,
                                   fmaf(sl, acc[3 * t + 2][pg][1], oreg[t][pg]));
            }
        }
    }

    // write: lane owns channels o = q*8 + 2fi + t (o==31 is pad -> skip)
    #pragma unroll
    for (int t = 0; t < 2; ++t) {
        const int o = q * 8 + 2 * fi + t;
        if (o < OUT_CH) {
            #pragma unroll
            for (int pg = 0; pg < 2; ++pg) {
                size_t gi = (size_t)o * NPIX + row * 128 + xq * 32 + pg * 16 + pix16;
                if (addf) dst[gi] += oreg[t][pg];
                else      dst[gi]  = oreg[t][pg];
            }
        }
    }
}

__global__ void reduce_kernel(const float* __restrict__ p1, float* __restrict__ out) {
    int e = blockIdx.x * 256 + threadIdx.x;
    if (e < OUT_CH * NPIX) out[e] += p1[e];
}

extern "C" void kernel_launch(void* const* d_in, const int* in_sizes, int n_in,
                              void* d_out, int out_size, void* d_ws, size_t ws_size,
                              hipStream_t stream) {
    const float* x  = (const float*)d_in[0];   // (1,31,128,128)
    const float* gw = (const float*)d_in[1];   // (9610,31,3,3)
    const float* gb = (const float*)d_in[2];   // (9610,)
    float* outp = (float*)d_out;               // (1,31,128,128)
    unsigned short* bpack = (unsigned short*)d_ws;          // 6,856,704 B
    float* p1 = (float*)((char*)d_ws + BP3_B);

    hipFuncSetAttribute((const void*)main_kernel,
                        hipFuncAttributeMaxDynamicSharedMemorySize, LDS_BYTES);

    const int NMAIN = CHUNKS * NFRG * 64;                   // 47616
    pack_kernel<<<(NMAIN + 255) / 256, 256, 0, stream>>>(gw, gb, bpack);

    if (ws_size >= WS_NEED) {
        // 256 blocks = 128 rows x 2 cg (1 block/CU); cg0 -> out, cg1 -> p1
        main_kernel<<<256, 1024, LDS_BYTES, stream>>>(x, bpack, outp, p1, 1, 0, 0, 0);
        reduce_kernel<<<(OUT_CH * NPIX + 255) / 256, 256, 0, stream>>>(p1, outp);
    } else {
        // chained fallback: two sequential dispatches (128 blocks each) through d_out
        main_kernel<<<128, 1024, LDS_BYTES, stream>>>(x, bpack, outp, nullptr, 0, 0, 16, 0);
        main_kernel<<<128, 1024, LDS_BYTES, stream>>>(x, bpack, outp, nullptr, 0, 16, 15, 1);
    }
}

// Round 22
// 106.766 us; speedup vs baseline: 1.3180x; 1.3180x over previous
//
#include <hip/hip_runtime.h>
#include <hip/hip_bf16.h>

// ---- problem constants ----
#define OUT_CH   31
#define COEF_LEN 7688                 // 31*31*8
#define NPIX     16384                // 128*128
#define CHUNKS   31                   // KAN input channels (independent param groups)
#define NFRG     24                   // param fragments per chunk (384 padded M rows)
#define NR       9                    // K-steps: r = ky*3+kx; k-in-step = conv channel ci
#define FRAG_U16 512                  // u16 per fragment (64 lanes x 8)
#define STEP_U16 (NFRG*FRAG_U16)      // 12288 u16 per (chunk,r) step
#define BP3_B    ((size_t)CHUNKS*NR*STEP_U16*2)        // 6,856,704
#define P1_B     ((size_t)OUT_CH*NPIX*4)               // 2,031,616
#define WS_NEED  (BP3_B + P1_B)                        // 8,888,320

// dynamic-LDS layout (97,664 B total; 1 block/CU)
#define SLAB_OFF  0                   // u16 [390][32] = 24,960 B (XOR-chunk swizzled)
#define WT_OFF    24960               // f32 [128][132] = 67,584 B
#define SLT_OFF   92544               // u16 [128][20]  =  5,120 B
#define LDS_BYTES 97664

using f32x4 = __attribute__((ext_vector_type(4))) float;
using s16x8 = __attribute__((ext_vector_type(8))) short;

__device__ __forceinline__ unsigned short f2bf(float f) {
    unsigned int u = __float_as_uint(f);
    unsigned int r = (u + 0x7FFFu + ((u >> 16) & 1u)) >> 16;
    return (unsigned short)r;
}

// ---------------------------------------------------------------------------
// Pack gen_w/gen_b into bf16 A-fragment layout (R14-proven, unchanged).
// Bias folded into GEMM: slab slot 31 = 1.0; A[ci=31] at r==4 carries gb[p].
//  bp3[i][r][f][lane][8] bf16.  M-row m = lane&15; k-in-step ci = (lane>>4)*8+jj.
//  param identity: o = (m>>2)*8 + f/3, jslot = (f%3)*4 + (m&3)
//    jslot 0..7 = coef j, 8 = univ, 9 = res, 10..11 = zero pad
// ---------------------------------------------------------------------------
__global__ void pack_kernel(const float* __restrict__ gw, const float* __restrict__ gb,
                            unsigned short* __restrict__ bp) {
    const int NMAIN = CHUNKS * NFRG * 64;          // 47616
    int tt = blockIdx.x * 256 + threadIdx.x;
    if (tt >= NMAIN) return;
    int lane = tt & 63;
    int u = tt >> 6;
    int f = u % NFRG;
    int i = u / NFRG;
    int m = lane & 15, q8 = lane >> 4;
    int o = (m >> 2) * 8 + f / 3;
    int jslot = (f % 3) * 4 + (m & 3);
    int p = -1;
    if (o < OUT_CH && jslot < 10) {
        if (jslot < 8)       p = i * 248 + o * 8 + jslot;
        else if (jslot == 8) p = COEF_LEN + i * 31 + o;
        else                 p = COEF_LEN + 961 + i * 31 + o;
    }
    s16x8 vr[NR];
    #pragma unroll
    for (int r = 0; r < NR; ++r)
        #pragma unroll
        for (int jj = 0; jj < 8; ++jj) vr[r][jj] = 0;
    #pragma unroll
    for (int jj = 0; jj < 8; ++jj) {
        int ci = q8 * 8 + jj;
        if (p >= 0) {
            if (ci < 31) {
                const float* gr = gw + (long)p * 279 + ci * 9;
                #pragma unroll
                for (int r = 0; r < NR; ++r) vr[r][jj] = (short)f2bf(gr[r]);
            } else {
                vr[4][jj] = (short)f2bf(gb[p]);   // bias channel, center tap only
            }
        }
    }
    #pragma unroll
    for (int r = 0; r < NR; ++r)
        *reinterpret_cast<s16x8*>(bp + (((size_t)i * NR + r) * NFRG + f) * FRAG_U16 + lane * 8) = vr[r];
}

// ---------------------------------------------------------------------------
// Fused conv-GEMM + KAN epilogue. R20 structure verbatim (96 us main,
// 1024-thr = 8 fi x 2 ph waves, 3 frags x 4 pg per wave, 1 block/CU)
// + XOR-CHUNK-SWIZZLED SLAB to kill the 8-bank concentration:
//   R20 bank math: lane bank = (pix16*20 + q*4) mod 32 -> all 64 lanes on
//   8 banks -> ~32 cyc per wave b128 (9.3M conflict cycles, ~15 us/CU).
//   New layout: row = 32 u16 (64 B; chunks 32-39 were dead pad), chunk c of
//   row R stored at position c ^ (R&3). Read: row*64 + ((q^(R&3))<<4).
//   Windows 16*(R&1)+4*(q^R&3) cover all 32 banks, 8 lanes each ->
//   CONFLICT-FREE (8-cyc minimum). px&3 == pix16&3 for every pg, so the 4
//   swizzle values are precomputed per lane and indexed by compile-time cr&3.
// Everything else R20-verbatim (pack, tables, cg L2 pin, partials+reduce).
// ---------------------------------------------------------------------------
__global__ void __launch_bounds__(1024, 1)
main_kernel(const float* __restrict__ x, const unsigned short* __restrict__ bp3,
            float* __restrict__ dst0, float* __restrict__ dst1,
            int two_cg, int c0_in, int nc_in, int add_in) {
    extern __shared__ char smem[];
    unsigned short* slab = (unsigned short*)(smem + SLAB_OFF);  // [390][32] swizzled
    float* Wt = (float*)(smem + WT_OFF);                        // [128][132]
    unsigned short* SLt = (unsigned short*)(smem + SLT_OFF);    // [128][20]

    const int tid = threadIdx.x;
    const int bid = blockIdx.x;
    int row, c0, nc, addf;
    float* dst;
    if (two_cg) {
        int cg = bid & 1;          // XCD = bid%8 -> cg fixed per XCD (L2 pin)
        row = bid >> 1;
        c0 = cg ? 16 : 0;
        nc = cg ? 15 : 16;
        dst = cg ? dst1 : dst0;
        addf = 0;
    } else {
        row = bid;
        c0 = c0_in; nc = nc_in; dst = dst0; addf = add_in;
    }

    // slab build: image rows row-1..row+1, cols -1..128; slot31 = 1.0 (bias).
    // slot s of slab-row R stored at u16 index R*32 + ((s>>3)^(R&3))*8 + (s&7).
    for (int idx = tid; idx < 3 * 130 * 32; idx += 1024) {
        int slot = idx & 31;
        int rix = idx >> 5;            // slab row R = rr*130 + cc
        int cc = rix % 130;
        int rr = rix / 130;
        int hh = row - 1 + rr, ww = cc - 1;
        unsigned short v = 0;
        if (slot < 31) {
            if ((unsigned)hh < 128u && (unsigned)ww < 128u)
                v = f2bf(x[slot * NPIX + hh * 128 + ww]);
        } else {
            v = 0x3F80;   // slot 31: 1.0 bf16 (bias column)
        }
        slab[rix * 32 + (((slot >> 3) ^ (rix & 3)) << 3) + (slot & 7)] = v;
    }

    // spline/silu tables: once per (pixel, chunk), from f32 x (center pixels)
    for (int idx = tid; idx < nc * 128; idx += 1024) {
        int px = idx & 127;
        int k = idx >> 7;
        float xv = x[(size_t)(c0 + k) * NPIX + row * 128 + px];
        float u5 = (xv + 1.0f) * 2.5f;
        float cf = fminf(fmaxf(floorf(u5), 0.f), 4.f);
        int ccb = (int)cf;
        float t = u5 - cf;
        float omt = 1.f - t;
        float t2v = t * t, t3v = t2v * t;
        float bw0 = omt * omt * omt * (1.f / 6.f);
        float bw3 = t3v * (1.f / 6.f);
        float bw1 = 0.5f * t3v - t2v + (2.f / 3.f);
        float bw2 = 1.f - bw0 - bw1 - bw3;         // partition of unity
        float* wr = Wt + px * 132 + k * 8;
        *reinterpret_cast<f32x4*>(wr) = (f32x4){0.f, 0.f, 0.f, 0.f};
        *reinterpret_cast<f32x4*>(wr + 4) = (f32x4){0.f, 0.f, 0.f, 0.f};
        wr[ccb] = bw0; wr[ccb + 1] = bw1; wr[ccb + 2] = bw2; wr[ccb + 3] = bw3;
        SLt[px * 20 + k] = f2bf(xv / (1.f + __expf(-xv)));
    }
    __syncthreads();
    // ---- no further barriers; slab/Wt/SLt are read-only below ----

    const int lane = tid & 63;
    const int w = tid >> 6;               // 0..15
    const int fi = w & 7;                 // frag triple [3fi, 3fi+3)
    const int ph = w >> 3;                // pixel half: cols [64*ph, 64*ph+64)
    const int q = lane >> 4;
    const int pix16 = lane & 15;
    const char* slabb = (const char*)slab;

    // swizzled-read precompute: px&3 == pix16&3 for all pg (ph*64, pg*16 ≡ 0 mod 4)
    const int rb3 = pix16 & 3;
    int swzt[4];
    #pragma unroll
    for (int c = 0; c < 4; ++c)
        swzt[c] = (q ^ ((rb3 + c) & 3)) << 4;
    int rb64[4];
    #pragma unroll
    for (int pg = 0; pg < 4; ++pg)
        rb64[pg] = (ph * 64 + pg * 16 + pix16) * 64;   // row base, 64 B/row

    float oreg[4] = {0.f, 0.f, 0.f, 0.f};

    #pragma unroll 1
    for (int k = 0; k < nc; ++k) {
        const unsigned short* aw = bp3
            + ((size_t)(c0 + k) * NR * NFRG + fi * 3) * FRAG_U16 + lane * 8;

        s16x8 pa[2][3];
        #pragma unroll
        for (int fl = 0; fl < 3; ++fl)
            pa[0][fl] = *reinterpret_cast<const s16x8*>(aw + fl * FRAG_U16);

        f32x4 acc[3][4];
        #pragma unroll
        for (int fl = 0; fl < 3; ++fl)
            #pragma unroll
            for (int pg = 0; pg < 4; ++pg)
                acc[fl][pg] = (f32x4){0.f, 0.f, 0.f, 0.f};   // bias comes via GEMM

        #pragma unroll
        for (int r = 0; r < NR; ++r) {
            if (r + 1 < NR) {    // reg-dbuf prefetch; static index (r unrolled)
                #pragma unroll
                for (int fl = 0; fl < 3; ++fl)
                    pa[(r + 1) & 1][fl] = *reinterpret_cast<const s16x8*>(
                        aw + (r + 1) * STEP_U16 + fl * FRAG_U16);
            }
            const int cr = (r / 3) * 130 + (r % 3);      // compile-time per r
            s16x8 pbv[4];
            #pragma unroll
            for (int pg = 0; pg < 4; ++pg)
                pbv[pg] = *reinterpret_cast<const s16x8*>(
                    slabb + rb64[pg] + cr * 64 + swzt[cr & 3]);

            __builtin_amdgcn_s_setprio(1);
            #pragma unroll
            for (int fl = 0; fl < 3; ++fl)
                #pragma unroll
                for (int pg = 0; pg < 4; ++pg)
                    acc[fl][pg] = __builtin_amdgcn_mfma_f32_16x16x32_bf16(
                        pa[r & 1][fl], pbv[pg], acc[fl][pg], 0, 0, 0);
            __builtin_amdgcn_s_setprio(0);
        }

        // table epilogue: 2 b128 + 1 b16 LDS reads + 10 fma per pg
        #pragma unroll
        for (int pg = 0; pg < 4; ++pg) {
            const int px = ph * 64 + pg * 16 + pix16;
            const float* wr = Wt + px * 132 + k * 8;
            f32x4 wlo = *reinterpret_cast<const f32x4*>(wr);
            f32x4 whi = *reinterpret_cast<const f32x4*>(wr + 4);
            unsigned short slb = SLt[px * 20 + k];
            float sl = __uint_as_float((unsigned)slb << 16);
            float sp = wlo[0] * acc[0][pg][0];
            sp = fmaf(wlo[1], acc[0][pg][1], sp);
            sp = fmaf(wlo[2], acc[0][pg][2], sp);
            sp = fmaf(wlo[3], acc[0][pg][3], sp);
            sp = fmaf(whi[0], acc[1][pg][0], sp);
            sp = fmaf(whi[1], acc[1][pg][1], sp);
            sp = fmaf(whi[2], acc[1][pg][2], sp);
            sp = fmaf(whi[3], acc[1][pg][3], sp);
            oreg[pg] = fmaf(acc[2][pg][0], sp, fmaf(sl, acc[2][pg][1], oreg[pg]));
        }
    }

    // write: lane's single output channel o = q*8 + fi (o==31 is pad -> skip)
    const int o = q * 8 + fi;
    if (o < OUT_CH) {
        #pragma unroll
        for (int pg = 0; pg < 4; ++pg) {
            size_t gi = (size_t)o * NPIX + row * 128 + ph * 64 + pg * 16 + pix16;
            if (addf) dst[gi] += oreg[pg];
            else      dst[gi]  = oreg[pg];
        }
    }
}

__global__ void reduce_kernel(const float* __restrict__ p1, float* __restrict__ out) {
    int e = blockIdx.x * 256 + threadIdx.x;
    if (e < OUT_CH * NPIX) out[e] += p1[e];
}

extern "C" void kernel_launch(void* const* d_in, const int* in_sizes, int n_in,
                              void* d_out, int out_size, void* d_ws, size_t ws_size,
                              hipStream_t stream) {
    const float* x  = (const float*)d_in[0];   // (1,31,128,128)
    const float* gw = (const float*)d_in[1];   // (9610,31,3,3)
    const float* gb = (const float*)d_in[2];   // (9610,)
    float* outp = (float*)d_out;               // (1,31,128,128)
    unsigned short* bpack = (unsigned short*)d_ws;          // 6,856,704 B
    float* p1 = (float*)((char*)d_ws + BP3_B);

    hipFuncSetAttribute((const void*)main_kernel,
                        hipFuncAttributeMaxDynamicSharedMemorySize, LDS_BYTES);

    const int NMAIN = CHUNKS * NFRG * 64;                   // 47616
    pack_kernel<<<(NMAIN + 255) / 256, 256, 0, stream>>>(gw, gb, bpack);

    if (ws_size >= WS_NEED) {
        // 256 blocks = 128 rows x 2 cg (1 block/CU); cg0 -> out, cg1 -> p1
        main_kernel<<<256, 1024, LDS_BYTES, stream>>>(x, bpack, outp, p1, 1, 0, 0, 0);
        reduce_kernel<<<(OUT_CH * NPIX + 255) / 256, 256, 0, stream>>>(p1, outp);
    } else {
        // chained fallback: two sequential dispatches (128 blocks each) through d_out
        main_kernel<<<128, 1024, LDS_BYTES, stream>>>(x, bpack, outp, nullptr, 0, 0, 16, 0);
        main_kernel<<<128, 1024, LDS_BYTES, stream>>>(x, bpack, outp, nullptr, 0, 16, 15, 1);
    }
}